// Round 19
// baseline (73.974 us; speedup 1.0000x reference)
//
#include <hip/hip_runtime.h>
#include <hip/hip_bf16.h>
#include <hip/hip_fp16.h>
#include <stdint.h>

typedef __attribute__((ext_vector_type(8))) short short8;
typedef __attribute__((ext_vector_type(8))) _Float16 half8;
typedef __attribute__((ext_vector_type(2))) __fp16 fp16x2;
typedef __attribute__((ext_vector_type(4))) float f32x4;
typedef __attribute__((ext_vector_type(16))) float f32x16;
typedef __attribute__((ext_vector_type(2))) unsigned int uintx2;

#define NB 8
#define RROWS 3072
#define TROWS 1024
#define FEAT 256
#define FK 192
#define NCHUNK 12
#define CROWS 256               // 3072/12
#define CITERS 8                // 256/32
#define TT 128

#define GLOAD_LDS16(src, dst)                                                  \
  __builtin_amdgcn_global_load_lds(                                            \
      (const __attribute__((address_space(1))) void*)(src),                    \
      (__attribute__((address_space(3))) void*)(dst), 16, 0, 0)

// packed RNE f32x2 -> bf16x2 (compiler emits v_cvt_pk_bf16_f32)
static __device__ __forceinline__ uint32_t pk2(float a, float b) {
  union { __hip_bfloat162 h; uint32_t u; } cv;
  cv.h = __float22bfloat162_rn(make_float2(a, b));
  return cv.u;
}
static __device__ __forceinline__ unsigned short f2bf(float x) {
  return (unsigned short)pk2(x, x);
}
static __device__ __forceinline__ float bfhi(uint32_t pk_lohalf_shifted) {
  union { uint32_t u; float f; } v; v.u = pk_lohalf_shifted;
  return v.f;
}

// ---------------- Stage 0: transpose weights to bf16 hi/lo [o][k] ------------
__global__ void wprep_kernel(const float* __restrict__ wf,
                             unsigned short* __restrict__ wth,
                             unsigned short* __restrict__ wtl) {
  const int o = blockIdx.x, k = threadIdx.x;  // 256 blocks x 192 thr
  const float v = wf[(size_t)k * 256 + o];
  const uint32_t hp = pk2(v, v);
  const float hf = bfhi(hp << 16);
  wth[(size_t)o * FK + k] = (unsigned short)hp;
  wtl[(size_t)o * FK + k] = f2bf(v - hf);
}

// ---------------- Stage 1: patch-embed conv via MFMA (bf16x2 3-pass) ---------
// Grid: 32 images x 16 blocks (64 patches each) = 512 blocks = 2/CU.
// Round-19: (a) 3 independent accumulators (chain 18 -> 6);
// (b) packed cvt_pkrtz fp16 hi/lo epilogue (type-fixed: __fp16 vector).
__global__ __launch_bounds__(256, 2) void feat_kernel(
    const float* __restrict__ ref, const float* __restrict__ tgt,
    const unsigned short* __restrict__ wth, const unsigned short* __restrict__ wtl,
    unsigned short* __restrict__ rh, unsigned short* __restrict__ rl,
    unsigned short* __restrict__ th, unsigned short* __restrict__ tl) {
  __shared__ unsigned short Ah[64 * 256];  // rows 512B (24 granules used), swizzled
  __shared__ unsigned short Al[64 * 256];
  const int tid = threadIdx.x;
  const int img = blockIdx.x >> 4;   // 0..31
  const int blk = blockIdx.x & 15;   // 16 image rows
  const int n = img >> 2, f = img & 3;
  const float* src = (f < 3) ? (ref + (size_t)(n * 3 + f) * (256 * 256 * 3))
                             : (tgt + (size_t)n * (256 * 256 * 3));
  const float* base = src + (size_t)blk * 16 * 768;

#pragma unroll
  for (int j = 0; j < 12; ++j) {
    const int f4 = tid + 256 * j;
    const int y  = f4 / 192;
    const int fl = (f4 - y * 192) * 4;
    const float4 v = *(const float4*)(base + (size_t)y * 768 + fl);
    const int p = ((y >> 3) << 5) + fl / 24;
    const int k = (y & 7) * 24 + fl % 24;
    const int byterow = k * 2;
    const int gr  = (byterow >> 4) ^ (p & 7);
    const int off = byterow & 15;
    uint2 hw, lw;
    hw.x = pk2(v.x, v.y);
    hw.y = pk2(v.z, v.w);
    lw.x = pk2(v.x - bfhi(hw.x << 16), v.y - bfhi(hw.x & 0xffff0000u));
    lw.y = pk2(v.z - bfhi(hw.y << 16), v.w - bfhi(hw.y & 0xffff0000u));
    *(uint2*)((char*)Ah + p * 512 + gr * 16 + off) = hw;
    *(uint2*)((char*)Al + p * 512 + gr * 16 + off) = lw;
  }
  __syncthreads();

  const int w = tid >> 6, lane = tid & 63, lr = lane & 15, kc = lane >> 4;
  const size_t base_row = (f < 3) ? ((size_t)n * RROWS + (size_t)f * 1024 + blk * 64)
                                  : ((size_t)n * TROWS + blk * 64);
  unsigned short* dh = (f < 3) ? rh : th;
  unsigned short* dl = (f < 3) ? rl : tl;

#pragma unroll
  for (int ot = 0; ot < 4; ++ot) {
    const int otile = w + 4 * ot;
    short8 bh[6], bl[6];
#pragma unroll
    for (int c = 0; c < 6; ++c) {
      const size_t boff = (size_t)(otile * 16 + lr) * FK + c * 32 + kc * 8;
      bh[c] = *(const short8*)(wth + boff);
      bl[c] = *(const short8*)(wtl + boff);
    }
#pragma unroll
    for (int pt = 0; pt < 4; ++pt) {
      // three independent accumulators: chains of 6 instead of 18
      f32x4 aH = {0.f, 0.f, 0.f, 0.f};
      f32x4 aM = {0.f, 0.f, 0.f, 0.f};
      f32x4 aL = {0.f, 0.f, 0.f, 0.f};
      const char* arow_h = (const char*)Ah + (pt * 16 + lr) * 512;
      const char* arow_l = (const char*)Al + (pt * 16 + lr) * 512;
      const int sw = (lr & 7) << 4;
#pragma unroll
      for (int c = 0; c < 6; ++c) {
        const int aoff = ((c * 4 + kc) << 4) ^ sw;
        const short8 ah = *(const short8*)(arow_h + aoff);
        const short8 al = *(const short8*)(arow_l + aoff);
        aH = __builtin_amdgcn_mfma_f32_16x16x32_bf16(ah, bh[c], aH, 0, 0, 0);
        aM = __builtin_amdgcn_mfma_f32_16x16x32_bf16(al, bh[c], aM, 0, 0, 0);
        aL = __builtin_amdgcn_mfma_f32_16x16x32_bf16(ah, bl[c], aL, 0, 0, 0);
      }
      float acc[4];
#pragma unroll
      for (int i = 0; i < 4; ++i) acc[i] = (aH[i] + aM[i]) + aL[i];
      // packed fp16 hi/lo epilogue (RTZ pack; residual computed exactly in fp32)
#pragma unroll
      for (int q = 0; q < 2; ++q) {
        const float a0 = acc[2 * q], a1 = acc[2 * q + 1];
        union { fp16x2 h; uint32_t u; } hp, lp;
        hp.h = __builtin_amdgcn_cvt_pkrtz(a0, a1);
        const float r0 = a0 - (float)hp.h[0];
        const float r1 = a1 - (float)hp.h[1];
        lp.h = __builtin_amdgcn_cvt_pkrtz(r0, r1);
        const size_t P0 = base_row + pt * 16 + 4 * kc + 2 * q;
        const int colo = otile * 16 + lr;
        dh[P0 * 256 + colo]       = (unsigned short)(hp.u & 0xffffu);
        dh[(P0 + 1) * 256 + colo] = (unsigned short)(hp.u >> 16);
        dl[P0 * 256 + colo]       = (unsigned short)(lp.u & 0xffffu);
        dl[(P0 + 1) * 256 + colo] = (unsigned short)(lp.u >> 16);
      }
    }
  }
}

// ---------------- Stage 2a: flash via 32x32x16 f16 2-pass, fixed-max softmax -
// Grid: 768 blocks (8 XCD-pinned n x 8 t-tiles(128) x 12 chunks) = 3/CU.
// (r17 verbatim — working, <42 us)
__global__ __launch_bounds__(256, 3) void flash_kernel(
    const unsigned short* __restrict__ rh, const unsigned short* __restrict__ rl,
    const unsigned short* __restrict__ th, const unsigned short* __restrict__ tl,
    const float* __restrict__ labels, float* __restrict__ part) {
  __shared__ unsigned short kh[8192], kl[8192];  // 32 rows x 256 fp16, single buf

  const int tid = threadIdx.x;
  const int bid = blockIdx.x;
  const int n   = bid & 7;                  // XCD-pinned batch
  const int tmp = bid >> 3;                 // 0..95
  const int tt  = tmp / NCHUNK;             // 0..7
  const int ch  = tmp - tt * NCHUNK;        // 0..11
  const int tbase = tt * TT;

  const int w = tid >> 6;                   // wave 0..3
  const int lane = tid & 63;
  const int col = lane & 31;                // t-col within wave's 32 (and C col)
  const int hi  = lane >> 5;                // k-subchunk selector
  const int cls = lane & 15;                // PV class

  const int rr = tid >> 5;                  // staging row&7
  const int cg = (tid & 31) ^ rr;           // pre-swizzled source granule

  const unsigned short* khs = rh + ((size_t)n * RROWS + ch * CROWS) * 256;
  const unsigned short* kls = rl + ((size_t)n * RROWS + ch * CROWS) * 256;
  const float* labsrc = labels + ((size_t)n * RROWS + ch * CROWS) * 16;

#define STAGE(itv)                                                             \
  do {                                                                         \
    const int rbase_ = (itv) * 32;                                             \
    _Pragma("unroll") for (int s = 0; s < 4; ++s) {                            \
      const int row_ = s * 8 + rr;                                             \
      const size_t goff_ = (size_t)(rbase_ + row_) * 256 + cg * 8;             \
      GLOAD_LDS16(khs + goff_, (char*)kh + s * 4096 + w * 1024);               \
      GLOAD_LDS16(kls + goff_, (char*)kl + s * 4096 + w * 1024);               \
    }                                                                          \
  } while (0)

  // Q B-fragments: single fp16, wave's 32 t-cols (64 VGPR)
  half8 qf[16];
  {
    const size_t qrow = (size_t)n * TROWS + tbase + 32 * w + col;
    const unsigned short* sh = th + qrow * 256 + hi * 8;
#pragma unroll
    for (int ks = 0; ks < 16; ++ks)
      qf[ks] = *(const half8*)(sh + ks * 16);
  }

  float lsum = 0.f;
  f32x16 opv = {};                          // D[t'][class], C-layout
  const int row7 = col & 7;                 // A-read row = col (lane&31)

  for (int it = 0; it < CITERS; ++it) {
    const int rbase = it * 32;
    __syncthreads();                        // all waves done reading prev tile
    STAGE(it);
    // labels for this tile -> registers (issued under the DMA)
    float lv[16];
#pragma unroll
    for (int j = 0; j < 8; ++j) {
      lv[j]     = labsrc[(size_t)(rbase + hi * 8 + j) * 16 + cls];
      lv[8 + j] = labsrc[(size_t)(rbase + 16 + hi * 8 + j) * 16 + cls];
    }
    __syncthreads();                        // DMA drained: tile visible

    // ---- QK^T via 32x32x16 f16: S[r][t], fp16 2-pass (K hi+lo, Q single) ----
    const char* kb_h = (const char*)kh + col * 512;
    const char* kb_l = (const char*)kl + col * 512;
    f32x16 acc = {};
#pragma unroll
    for (int ks = 0; ks < 16; ++ks) {
      const int off = ((2 * ks + hi) ^ row7) << 4;
      const half8 ah = *(const half8*)(kb_h + off);
      const half8 al = *(const half8*)(kb_l + off);
      acc = __builtin_amdgcn_mfma_f32_32x32x16_f16(ah, qf[ks], acc, 0, 0, 0);
      acc = __builtin_amdgcn_mfma_f32_32x32x16_f16(al, qf[ks], acc, 0, 0, 0);
    }
    // lane holds S[r(reg,hi)][t=col], r = (reg&3)+8*(reg>>2)+4*hi

    // ---- fixed-max softmax: P = exp(S - 20), no reductions in-loop ----
    float e[16], ts = 0.f;
#pragma unroll
    for (int i = 0; i < 16; ++i) { e[i] = __expf(acc[i] - 20.0f); ts += e[i]; }
    lsum += ts;

    // ---- P -> PV A-fragments: 4 x v_permlane32_swap (VALU pipe) ----
    uint32_t pw[8];
#pragma unroll
    for (int i = 0; i < 8; ++i) pw[i] = pk2(e[2 * i], e[2 * i + 1]);
    union { uint32_t u[4]; short8 s8; } A0, A1;
    {
      const uintx2 r0 = __builtin_amdgcn_permlane32_swap(pw[0], pw[2], false, false);
      const uintx2 r1 = __builtin_amdgcn_permlane32_swap(pw[1], pw[3], false, false);
      const uintx2 r2 = __builtin_amdgcn_permlane32_swap(pw[4], pw[6], false, false);
      const uintx2 r3 = __builtin_amdgcn_permlane32_swap(pw[5], pw[7], false, false);
      A0.u[0] = r0[0]; A0.u[2] = r0[1];
      A0.u[1] = r1[0]; A0.u[3] = r1[1];
      A1.u[0] = r2[0]; A1.u[2] = r2[1];
      A1.u[1] = r3[0]; A1.u[3] = r3[1];
    }

    // labels B-fragments: B[k=r][class], classes duplicated in cols 16-31
    union { uint32_t u[4]; short8 s8; } B0, B1;
#pragma unroll
    for (int i = 0; i < 4; ++i) {
      B0.u[i] = pk2(lv[2 * i], lv[2 * i + 1]);
      B1.u[i] = pk2(lv[8 + 2 * i], lv[8 + 2 * i + 1]);
    }

    // ---- PV: out[t][class] += P^T . labels (k = 32 rows in 2 steps, bf16) ----
    opv = __builtin_amdgcn_mfma_f32_32x32x16_bf16(A0.s8, B0.s8, opv, 0, 0, 0);
    opv = __builtin_amdgcn_mfma_f32_32x32x16_bf16(A1.s8, B1.s8, opv, 0, 0, 0);
  }

  // epilogue: partials [t][ m=20, l, 16 classes ]
  const float ltot = lsum + __shfl_xor(lsum, 32);
  float* pb = part + ((size_t)(n * 8 + tt) * NCHUNK + ch) * (TT * 18);
  if (col < 16) {
#pragma unroll
    for (int reg = 0; reg < 16; ++reg) {
      const int t = (reg & 3) + 8 * (reg >> 2) + 4 * hi;
      pb[(32 * w + t) * 18 + 2 + col] = opv[reg];
    }
  }
  if (lane < 32) {
    pb[(32 * w + lane) * 18] = 20.0f;
    pb[(32 * w + lane) * 18 + 1] = ltot;
  }
#undef STAGE
}

// ---------------- Stage 2b: combine chunk partials ---------------------------
// Grid: 8 n x 8 t-tiles x 2 halves = 128 blocks x 256 thr.
__global__ __launch_bounds__(256) void combine_kernel(
    const float* __restrict__ part, float* __restrict__ out) {
  const int tid = threadIdx.x;
  const int tw = tid >> 2, g = tid & 3;
  const int half = blockIdx.x & 1, tt = (blockIdx.x >> 1) & 7, n = blockIdx.x >> 4;
  const float* pb = part + (size_t)((n * 8 + tt) * NCHUNK) * (TT * 18) +
                    (half * 64 + tw) * 18;
  float M = -3.0e38f;
#pragma unroll
  for (int c = 0; c < NCHUNK; ++c) M = fmaxf(M, pb[c * TT * 18]);
  float L = 0.f, o0 = 0.f, o1 = 0.f, o2 = 0.f, o3 = 0.f;
#pragma unroll
  for (int c = 0; c < NCHUNK; ++c) {
    const float* p = pb + c * TT * 18;
    const float wgt = __expf(p[0] - M);
    L  = fmaf(p[1], wgt, L);
    o0 = fmaf(p[2 + 4 * g + 0], wgt, o0);
    o1 = fmaf(p[2 + 4 * g + 1], wgt, o1);
    o2 = fmaf(p[2 + 4 * g + 2], wgt, o2);
    o3 = fmaf(p[2 + 4 * g + 3], wgt, o3);
  }
  const float inv = 1.f / L;
  float4 ov; ov.x = o0 * inv; ov.y = o1 * inv; ov.z = o2 * inv; ov.w = o3 * inv;
  *(float4*)&out[((size_t)n * TROWS + tt * TT + half * 64 + tw) * 16 + 4 * g] = ov;
}

extern "C" void kernel_launch(void* const* d_in, const int* in_sizes, int n_in,
                              void* d_out, int out_size, void* d_ws, size_t ws_size,
                              hipStream_t stream) {
  const float* ref    = (const float*)d_in[0];
  const float* tgt    = (const float*)d_in[1];
  const float* labels = (const float*)d_in[2];
  const float* wf     = (const float*)d_in[3];
  float* out = (float*)d_out;

  unsigned short* rh  = (unsigned short*)d_ws;
  unsigned short* rl  = rh + (size_t)NB * RROWS * FEAT;
  unsigned short* th  = rl + (size_t)NB * RROWS * FEAT;
  unsigned short* tl  = th + (size_t)NB * TROWS * FEAT;
  unsigned short* wth = tl + (size_t)NB * TROWS * FEAT;
  unsigned short* wtl = wth + (size_t)FEAT * FK;
  float* part = (float*)(wtl + (size_t)FEAT * FK);

  hipLaunchKernelGGL(wprep_kernel, dim3(256), dim3(192), 0, stream, wf, wth, wtl);
  hipLaunchKernelGGL(feat_kernel, dim3(512), dim3(256), 0, stream,
                     ref, tgt, wth, wtl, rh, rl, th, tl);
  hipLaunchKernelGGL(flash_kernel, dim3(8 * 8 * NCHUNK), dim3(256), 0, stream,
                     rh, rl, th, tl, labels, part);
  hipLaunchKernelGGL(combine_kernel, dim3(128), dim3(256), 0, stream,
                     part, out);
}

// Round 20
// 56.092 us; speedup vs baseline: 1.3188x; 1.3188x over previous
//
#include <hip/hip_runtime.h>
#include <hip/hip_bf16.h>
#include <hip/hip_fp16.h>
#include <stdint.h>

typedef __attribute__((ext_vector_type(8))) short short8;
typedef __attribute__((ext_vector_type(8))) _Float16 half8;
typedef __attribute__((ext_vector_type(4))) float f32x4;
typedef __attribute__((ext_vector_type(16))) float f32x16;
typedef __attribute__((ext_vector_type(2))) unsigned int uintx2;

#define NB 8
#define RROWS 3072
#define TROWS 1024
#define FEAT 256
#define FK 192
#define NCHUNK 12
#define CROWS 256               // 3072/12
#define CITERS 8                // 256/32
#define TT 128

#define GLOAD_LDS16(src, dst)                                                  \
  __builtin_amdgcn_global_load_lds(                                            \
      (const __attribute__((address_space(1))) void*)(src),                    \
      (__attribute__((address_space(3))) void*)(dst), 16, 0, 0)

// packed RNE f32x2 -> bf16x2 (compiler emits v_cvt_pk_bf16_f32)
static __device__ __forceinline__ uint32_t pk2(float a, float b) {
  union { __hip_bfloat162 h; uint32_t u; } cv;
  cv.h = __float22bfloat162_rn(make_float2(a, b));
  return cv.u;
}
static __device__ __forceinline__ unsigned short f2bf(float x) {
  return (unsigned short)pk2(x, x);
}
static __device__ __forceinline__ float bfhi(uint32_t pk_lohalf_shifted) {
  union { uint32_t u; float f; } v; v.u = pk_lohalf_shifted;
  return v.f;
}

// ---------------- Stage 0: transpose weights to bf16 hi/lo [o][k] ------------
__global__ void wprep_kernel(const float* __restrict__ wf,
                             unsigned short* __restrict__ wth,
                             unsigned short* __restrict__ wtl) {
  const int o = blockIdx.x, k = threadIdx.x;  // 256 blocks x 192 thr
  const float v = wf[(size_t)k * 256 + o];
  const uint32_t hp = pk2(v, v);
  const float hf = bfhi(hp << 16);
  wth[(size_t)o * FK + k] = (unsigned short)hp;
  wtl[(size_t)o * FK + k] = f2bf(v - hf);
}

// ---------------- Stage 1: patch-embed conv via MFMA (bf16x2 3-pass) ---------
// Grid: 32 images x 16 blocks (64 patches each) = 512 blocks = 2/CU.
// Features now stored as SINGLE fp16 (RNE) — rl/tl eliminated (writes halved).
__global__ __launch_bounds__(256, 2) void feat_kernel(
    const float* __restrict__ ref, const float* __restrict__ tgt,
    const unsigned short* __restrict__ wth, const unsigned short* __restrict__ wtl,
    unsigned short* __restrict__ rh, unsigned short* __restrict__ th) {
  __shared__ unsigned short Ah[64 * 256];  // rows 512B (24 granules used), swizzled
  __shared__ unsigned short Al[64 * 256];
  const int tid = threadIdx.x;
  const int img = blockIdx.x >> 4;   // 0..31
  const int blk = blockIdx.x & 15;   // 16 image rows
  const int n = img >> 2, f = img & 3;
  const float* src = (f < 3) ? (ref + (size_t)(n * 3 + f) * (256 * 256 * 3))
                             : (tgt + (size_t)n * (256 * 256 * 3));
  const float* base = src + (size_t)blk * 16 * 768;

#pragma unroll
  for (int j = 0; j < 12; ++j) {
    const int f4 = tid + 256 * j;
    const int y  = f4 / 192;
    const int fl = (f4 - y * 192) * 4;
    const float4 v = *(const float4*)(base + (size_t)y * 768 + fl);
    const int p = ((y >> 3) << 5) + fl / 24;
    const int k = (y & 7) * 24 + fl % 24;
    const int byterow = k * 2;
    const int gr  = (byterow >> 4) ^ (p & 7);
    const int off = byterow & 15;
    uint2 hw, lw;
    hw.x = pk2(v.x, v.y);
    hw.y = pk2(v.z, v.w);
    lw.x = pk2(v.x - bfhi(hw.x << 16), v.y - bfhi(hw.x & 0xffff0000u));
    lw.y = pk2(v.z - bfhi(hw.y << 16), v.w - bfhi(hw.y & 0xffff0000u));
    *(uint2*)((char*)Ah + p * 512 + gr * 16 + off) = hw;
    *(uint2*)((char*)Al + p * 512 + gr * 16 + off) = lw;
  }
  __syncthreads();

  const int w = tid >> 6, lane = tid & 63, lr = lane & 15, kc = lane >> 4;
  const size_t base_row = (f < 3) ? ((size_t)n * RROWS + (size_t)f * 1024 + blk * 64)
                                  : ((size_t)n * TROWS + blk * 64);
  unsigned short* dh = (f < 3) ? rh : th;

#pragma unroll
  for (int ot = 0; ot < 4; ++ot) {
    const int otile = w + 4 * ot;
    short8 bh[6], bl[6];
#pragma unroll
    for (int c = 0; c < 6; ++c) {
      const size_t boff = (size_t)(otile * 16 + lr) * FK + c * 32 + kc * 8;
      bh[c] = *(const short8*)(wth + boff);
      bl[c] = *(const short8*)(wtl + boff);
    }
#pragma unroll
    for (int pt = 0; pt < 4; ++pt) {
      f32x4 acc = {0.f, 0.f, 0.f, 0.f};
      const char* arow_h = (const char*)Ah + (pt * 16 + lr) * 512;
      const char* arow_l = (const char*)Al + (pt * 16 + lr) * 512;
      const int sw = (lr & 7) << 4;
#pragma unroll
      for (int c = 0; c < 6; ++c) {
        const int aoff = ((c * 4 + kc) << 4) ^ sw;
        const short8 ah = *(const short8*)(arow_h + aoff);
        const short8 al = *(const short8*)(arow_l + aoff);
        acc = __builtin_amdgcn_mfma_f32_16x16x32_bf16(ah, bh[c], acc, 0, 0, 0);
        acc = __builtin_amdgcn_mfma_f32_16x16x32_bf16(al, bh[c], acc, 0, 0, 0);
        acc = __builtin_amdgcn_mfma_f32_16x16x32_bf16(ah, bl[c], acc, 0, 0, 0);
      }
#pragma unroll
      for (int i = 0; i < 4; ++i) {
        const size_t P = base_row + pt * 16 + 4 * kc + i;
        dh[P * 256 + otile * 16 + lr] = __half_as_ushort(__float2half(acc[i]));
      }
    }
  }
}

// ---------------- Stage 2a: flash via 32x32x16 f16 single-pass QK ------------
// Grid: 768 blocks (8 XCD-pinned n x 8 t-tiles(128) x 12 chunks) = 3/CU.
// K = single fp16, DOUBLE-buffered (2 x 16 KB LDS). One barrier per iter.
// QK = 16 MFMA/wave-iter (half of r17); DS reads halved.
__global__ __launch_bounds__(256, 3) void flash_kernel(
    const unsigned short* __restrict__ rh, const unsigned short* __restrict__ th,
    const float* __restrict__ labels, float* __restrict__ part) {
  __shared__ unsigned short kh[2][8192];    // [buf][32 rows x 256 fp16]

  const int tid = threadIdx.x;
  const int bid = blockIdx.x;
  const int n   = bid & 7;                  // XCD-pinned batch
  const int tmp = bid >> 3;                 // 0..95
  const int tt  = tmp / NCHUNK;             // 0..7
  const int ch  = tmp - tt * NCHUNK;        // 0..11
  const int tbase = tt * TT;

  const int w = tid >> 6;                   // wave 0..3
  const int lane = tid & 63;
  const int col = lane & 31;                // t-col within wave's 32 (and C col)
  const int hi  = lane >> 5;                // k-subchunk selector
  const int cls = lane & 15;                // PV class

  const int rr = tid >> 5;                  // staging row&7
  const int cg = (tid & 31) ^ rr;           // pre-swizzled source granule

  const unsigned short* khs = rh + ((size_t)n * RROWS + ch * CROWS) * 256;
  const float* labsrc = labels + ((size_t)n * RROWS + ch * CROWS) * 16;

#define STAGE(buf, itv)                                                        \
  do {                                                                         \
    const int rbase_ = (itv) * 32;                                             \
    _Pragma("unroll") for (int s = 0; s < 4; ++s) {                            \
      const int row_ = s * 8 + rr;                                             \
      const size_t goff_ = (size_t)(rbase_ + row_) * 256 + cg * 8;             \
      GLOAD_LDS16(khs + goff_, (char*)kh[buf] + s * 4096 + w * 1024);          \
    }                                                                          \
  } while (0)

  // Q B-fragments: single fp16, wave's 32 t-cols (64 VGPR)
  half8 qf[16];
  {
    const size_t qrow = (size_t)n * TROWS + tbase + 32 * w + col;
    const unsigned short* sh = th + qrow * 256 + hi * 8;
#pragma unroll
    for (int ks = 0; ks < 16; ++ks)
      qf[ks] = *(const half8*)(sh + ks * 16);
  }

  STAGE(0, 0);
  __syncthreads();                          // drains buf0 DMA

  float lsum = 0.f;
  f32x16 opv = {};                          // D[t'][class], C-layout
  const int row7 = col & 7;                 // A-read row = col (lane&31)

  for (int it = 0; it < CITERS; ++it) {
    const int rbase = it * 32;
    // labels for this tile -> registers (issued early, hides under QK)
    float lv[16];
#pragma unroll
    for (int j = 0; j < 8; ++j) {
      lv[j]     = labsrc[(size_t)(rbase + hi * 8 + j) * 16 + cls];
      lv[8 + j] = labsrc[(size_t)(rbase + 16 + hi * 8 + j) * 16 + cls];
    }
    if (it + 1 < CITERS) STAGE((it + 1) & 1, it + 1);

    // ---- QK^T via 32x32x16 f16 single pass: S[r][t] ----
    const char* kb = (const char*)kh[it & 1] + col * 512;
    f32x16 acc = {};
#pragma unroll
    for (int ks = 0; ks < 16; ++ks) {
      const int off = ((2 * ks + hi) ^ row7) << 4;
      const half8 ah = *(const half8*)(kb + off);
      acc = __builtin_amdgcn_mfma_f32_32x32x16_f16(ah, qf[ks], acc, 0, 0, 0);
    }
    // lane holds S[r(reg,hi)][t=col], r = (reg&3)+8*(reg>>2)+4*hi

    // ---- fixed-max softmax: P = exp(S - 20), no reductions in-loop ----
    float e[16], ts = 0.f;
#pragma unroll
    for (int i = 0; i < 16; ++i) { e[i] = __expf(acc[i] - 20.0f); ts += e[i]; }
    lsum += ts;

    // ---- P -> PV A-fragments: 4 x v_permlane32_swap (VALU pipe) ----
    uint32_t pw[8];
#pragma unroll
    for (int i = 0; i < 8; ++i) pw[i] = pk2(e[2 * i], e[2 * i + 1]);
    union { uint32_t u[4]; short8 s8; } A0, A1;
    {
      const uintx2 r0 = __builtin_amdgcn_permlane32_swap(pw[0], pw[2], false, false);
      const uintx2 r1 = __builtin_amdgcn_permlane32_swap(pw[1], pw[3], false, false);
      const uintx2 r2 = __builtin_amdgcn_permlane32_swap(pw[4], pw[6], false, false);
      const uintx2 r3 = __builtin_amdgcn_permlane32_swap(pw[5], pw[7], false, false);
      A0.u[0] = r0[0]; A0.u[2] = r0[1];
      A0.u[1] = r1[0]; A0.u[3] = r1[1];
      A1.u[0] = r2[0]; A1.u[2] = r2[1];
      A1.u[1] = r3[0]; A1.u[3] = r3[1];
    }

    // labels B-fragments: B[k=r][class], classes duplicated in cols 16-31
    union { uint32_t u[4]; short8 s8; } B0, B1;
#pragma unroll
    for (int i = 0; i < 4; ++i) {
      B0.u[i] = pk2(lv[2 * i], lv[2 * i + 1]);
      B1.u[i] = pk2(lv[8 + 2 * i], lv[8 + 2 * i + 1]);
    }

    // ---- PV: out[t][class] += P^T . labels (k = 32 rows in 2 steps, bf16) ----
    opv = __builtin_amdgcn_mfma_f32_32x32x16_bf16(A0.s8, B0.s8, opv, 0, 0, 0);
    opv = __builtin_amdgcn_mfma_f32_32x32x16_bf16(A1.s8, B1.s8, opv, 0, 0, 0);

    __syncthreads();  // drains next-tile DMA; guards buffer reuse
  }

  // epilogue: partials [t][ m=20, l, 16 classes ]
  const float ltot = lsum + __shfl_xor(lsum, 32);
  float* pb = part + ((size_t)(n * 8 + tt) * NCHUNK + ch) * (TT * 18);
  if (col < 16) {
#pragma unroll
    for (int reg = 0; reg < 16; ++reg) {
      const int t = (reg & 3) + 8 * (reg >> 2) + 4 * hi;
      pb[(32 * w + t) * 18 + 2 + col] = opv[reg];
    }
  }
  if (lane < 32) {
    pb[(32 * w + lane) * 18] = 20.0f;
    pb[(32 * w + lane) * 18 + 1] = ltot;
  }
#undef STAGE
}

// ---------------- Stage 2b: combine chunk partials ---------------------------
// Grid: 8 n x 8 t-tiles x 2 halves = 128 blocks x 256 thr.
__global__ __launch_bounds__(256) void combine_kernel(
    const float* __restrict__ part, float* __restrict__ out) {
  const int tid = threadIdx.x;
  const int tw = tid >> 2, g = tid & 3;
  const int half = blockIdx.x & 1, tt = (blockIdx.x >> 1) & 7, n = blockIdx.x >> 4;
  const float* pb = part + (size_t)((n * 8 + tt) * NCHUNK) * (TT * 18) +
                    (half * 64 + tw) * 18;
  float M = -3.0e38f;
#pragma unroll
  for (int c = 0; c < NCHUNK; ++c) M = fmaxf(M, pb[c * TT * 18]);
  float L = 0.f, o0 = 0.f, o1 = 0.f, o2 = 0.f, o3 = 0.f;
#pragma unroll
  for (int c = 0; c < NCHUNK; ++c) {
    const float* p = pb + c * TT * 18;
    const float wgt = __expf(p[0] - M);
    L  = fmaf(p[1], wgt, L);
    o0 = fmaf(p[2 + 4 * g + 0], wgt, o0);
    o1 = fmaf(p[2 + 4 * g + 1], wgt, o1);
    o2 = fmaf(p[2 + 4 * g + 2], wgt, o2);
    o3 = fmaf(p[2 + 4 * g + 3], wgt, o3);
  }
  const float inv = 1.f / L;
  float4 ov; ov.x = o0 * inv; ov.y = o1 * inv; ov.z = o2 * inv; ov.w = o3 * inv;
  *(float4*)&out[((size_t)n * TROWS + tt * TT + half * 64 + tw) * 16 + 4 * g] = ov;
}

extern "C" void kernel_launch(void* const* d_in, const int* in_sizes, int n_in,
                              void* d_out, int out_size, void* d_ws, size_t ws_size,
                              hipStream_t stream) {
  const float* ref    = (const float*)d_in[0];
  const float* tgt    = (const float*)d_in[1];
  const float* labels = (const float*)d_in[2];
  const float* wf     = (const float*)d_in[3];
  float* out = (float*)d_out;

  unsigned short* rh  = (unsigned short*)d_ws;
  unsigned short* th  = rh + (size_t)NB * RROWS * FEAT;
  unsigned short* wth = th + (size_t)NB * TROWS * FEAT;
  unsigned short* wtl = wth + (size_t)FEAT * FK;
  float* part = (float*)(wtl + (size_t)FEAT * FK);

  hipLaunchKernelGGL(wprep_kernel, dim3(256), dim3(192), 0, stream, wf, wth, wtl);
  hipLaunchKernelGGL(feat_kernel, dim3(512), dim3(256), 0, stream,
                     ref, tgt, wth, wtl, rh, th);
  hipLaunchKernelGGL(flash_kernel, dim3(8 * 8 * NCHUNK), dim3(256), 0, stream,
                     rh, th, labels, part);
  hipLaunchKernelGGL(combine_kernel, dim3(128), dim3(256), 0, stream,
                     part, out);
}